// Round 7
// baseline (579.936 us; speedup 1.0000x reference)
//
#include <hip/hip_runtime.h>

typedef unsigned short us;
typedef us us4 __attribute__((ext_vector_type(4)));
typedef us us8 __attribute__((ext_vector_type(8)));
typedef short bf16x8 __attribute__((ext_vector_type(8)));
typedef float f32x4 __attribute__((ext_vector_type(4)));

#define DEVI static __device__ __forceinline__

// constants for this problem instance
#define BB 16
#define NN 4096
#define PP 256
#define CC 8
#define MM (BB * NN)   // 65536

DEVI float bf2f(us u) { unsigned x = ((unsigned)u) << 16; return __builtin_bit_cast(float, x); }
DEVI us f2bf(float f) {
  unsigned x = __builtin_bit_cast(unsigned, f);
  x += 0x7fffu + ((x >> 16) & 1u);   // round to nearest even
  return (us)(x >> 16);
}

DEVI void gload_lds16(const void* g, void* l) {
  __builtin_amdgcn_global_load_lds(
      (const __attribute__((address_space(1))) void*)g,
      (__attribute__((address_space(3))) void*)l, 16, 0, 0);
}

DEVI float sigf(float x) { return 1.f / (1.f + __expf(-x)); }
DEVI float tanhfast(float a) {
  float aa = fabsf(a);
  float t = 1.f - 2.f / (1.f + __expf(2.f * aa));
  return copysignf(t, a);
}

// ---------------- weight prep: fp32 -> bf16, concatenated / gate-interleaved ----
// Wg layout (shuffle-free): row R -> J16 = R>>6, gate g = (R>>4)&3, c = R&15,
// output col j = J16*16 + c. Over K=512 ([h | s]):
//   g=0 (r):  [W_ih_r | W_hh_r]   g=1 (z): [W_ih_z | W_hh_z]
//   g=2 (xn): [W_ih_n | 0]        g=3 (hn): [0 | W_hh_n]
__global__ void k_prep(const float* __restrict__ Wres,
                       const float* __restrict__ Wpar, const float* __restrict__ bpar,
                       const float* __restrict__ Wnbr, const float* __restrict__ bnbr,
                       const float* __restrict__ Wih, const float* __restrict__ Whh,
                       const float* __restrict__ bih, const float* __restrict__ bhh,
                       us* __restrict__ Wr, us* __restrict__ Wcat, float* __restrict__ bcat,
                       us* __restrict__ Wg, float* __restrict__ bg) {
  int tid = blockIdx.x * blockDim.x + threadIdx.x;
  int nth = gridDim.x * blockDim.x;
  for (int i = tid; i < 256 * 256; i += nth) Wr[i] = f2bf(Wres[i]);
  for (int i = tid; i < 256 * 512; i += nth) {
    int o = i >> 9, k = i & 511;
    float v = (k < 256) ? Wpar[o * 256 + k] : Wnbr[o * 256 + (k - 256)];
    Wcat[i] = f2bf(v);
  }
  for (int i = tid; i < 256; i += nth) bcat[i] = bpar[i] + bnbr[i];
  for (int i = tid; i < 1024 * 512; i += nth) {
    int R = i >> 9, k = i & 511;
    int g = (R >> 4) & 3, j = ((R >> 6) << 4) + (R & 15);
    float v = 0.f;
    if (g == 0)      v = (k < 256) ? Wih[j * 256 + k]         : Whh[j * 256 + (k - 256)];
    else if (g == 1) v = (k < 256) ? Wih[(256 + j) * 256 + k] : Whh[(256 + j) * 256 + (k - 256)];
    else if (g == 2) v = (k < 256) ? Wih[(512 + j) * 256 + k] : 0.f;
    else             v = (k < 256) ? 0.f                      : Whh[(512 + j) * 256 + (k - 256)];
    Wg[i] = f2bf(v);
  }
  for (int i = tid; i < 1024; i += nth) {
    int g = (i >> 4) & 3, j = ((i >> 6) << 4) + (i & 15);
    float v;
    if (g == 0)      v = bih[j] + bhh[j];
    else if (g == 1) v = bih[256 + j] + bhh[256 + j];
    else if (g == 2) v = bih[512 + j];
    else             v = bhh[512 + j];
    bg[i] = v;
  }
}

// ---------------- x fp32 -> bf16 (vectorized) ----------------
__global__ __launch_bounds__(256) void k_f2bf(const float* __restrict__ x,
                                              us* __restrict__ o, int n8) {
  int i = blockIdx.x * blockDim.x + threadIdx.x;
  if (i >= n8) return;
  const float4* p = (const float4*)x + (size_t)i * 2;
  float4 a = p[0], b = p[1];
  us8 r;
  r[0] = f2bf(a.x); r[1] = f2bf(a.y); r[2] = f2bf(a.z); r[3] = f2bf(a.w);
  r[4] = f2bf(b.x); r[5] = f2bf(b.y); r[6] = f2bf(b.z); r[7] = f2bf(b.w);
  *(us8*)(o + (size_t)i * 8) = r;
}

// ---------------- gather: A_cat = [h[parent] | avg children h] (bf16) ----------
__global__ __launch_bounds__(256)
void k_gather(const us* __restrict__ h, const int* __restrict__ par,
              const int* __restrict__ chd, const int* __restrict__ cnt,
              us* __restrict__ Acat) {
  int wid = (blockIdx.x * blockDim.x + threadIdx.x) >> 6;  // one wave per node
  int l = threadIdx.x & 63;
  int m = wid;                       // 0..MM-1
  int b = m >> 12;                   // N = 4096
  int rowP = (b << 12) + par[m];
  us4 pv = *((const us4*)(h + ((size_t)rowP << 8)) + l);
  *((us4*)(Acat + ((size_t)m << 9)) + l) = pv;
  int c = cnt[m];
  float inv = 1.f / (float)c;
  const int* ch = chd + (size_t)m * CC;
  us4 cv[CC];
#pragma unroll
  for (int i = 0; i < CC; ++i) {
    int rowC = (b << 12) + ch[i];
    cv[i] = *((const us4*)(h + ((size_t)rowC << 8)) + l);
  }
  float a0 = 0.f, a1 = 0.f, a2 = 0.f, a3 = 0.f;
#pragma unroll
  for (int i = 0; i < CC; ++i) {
    float wgt = (i < c) ? 1.f : 0.f;
    a0 += wgt * bf2f(cv[i][0]); a1 += wgt * bf2f(cv[i][1]);
    a2 += wgt * bf2f(cv[i][2]); a3 += wgt * bf2f(cv[i][3]);
  }
  us4 nb;
  nb[0] = f2bf(a0 * inv); nb[1] = f2bf(a1 * inv);
  nb[2] = f2bf(a2 * inv); nb[3] = f2bf(a3 * inv);
  *((us4*)(Acat + ((size_t)m << 9) + 256) + l) = nb;
}

// ---------------- quadrant fragment loads / MFMA (phase building blocks) -------
template <int IH>
DEVI void quad_readA(const us* sAc, int wr, int l, bf16x8 (&af)[2][4]) {
#pragma unroll
  for (int ks = 0; ks < 2; ++ks)
#pragma unroll
    for (int i = 0; i < 4; ++i) {
      int row = wr * 128 + (IH * 4 + i) * 16 + (l & 15);
      int kb = ((ks * 32 + (l >> 4) * 8) * 2) ^ ((row & 7) << 4);  // swizzled read
      af[ks][i] = *(const bf16x8*)((const char*)sAc + row * 128 + kb);
    }
}
template <int JH, int M2>
DEVI void quad_readB(const us* sBc, int wc, int l, bf16x8 (&bfr)[2][2]) {
#pragma unroll
  for (int ks = 0; ks < 2; ++ks)
#pragma unroll
    for (int jj = 0; jj < 2; ++jj)
      if (M2 & (1 << jj)) {
        int row = wc * 64 + (JH * 2 + jj) * 16 + (l & 15);
        int kb = ((ks * 32 + (l >> 4) * 8) * 2) ^ ((row & 7) << 4);
        bfr[ks][jj] = *(const bf16x8*)((const char*)sBc + row * 128 + kb);
      }
}
template <int IH, int JH, int M2>
DEVI void quad_mma(const bf16x8 (&af)[2][4], const bf16x8 (&bfr)[2][2],
                   f32x4 (&acc)[8][4]) {
#pragma unroll
  for (int ks = 0; ks < 2; ++ks)
#pragma unroll
    for (int i = 0; i < 4; ++i)
#pragma unroll
      for (int jj = 0; jj < 2; ++jj)
        if (M2 & (1 << jj))
          acc[IH * 4 + i][JH * 2 + jj] = __builtin_amdgcn_mfma_f32_16x16x32_bf16(
              af[ks][i], bfr[ks][jj], acc[IH * 4 + i][JH * 2 + jj], 0, 0, 0);
}

DEVI void raw_barrier() {
  __builtin_amdgcn_sched_barrier(0);
  __builtin_amdgcn_s_barrier();      // RAW barrier: no implicit vmcnt(0) drain
  __builtin_amdgcn_sched_barrier(0);
}

// ---------------- GEMM: C = A @ Bw^T (+bias), 256x256 tile, 4-phase schedule ---
// m201-lineage phase interleave. Per K-tile, 4 phases = C-quadrants (ih,jh):
//   {ds_read quadrant frags (af reused across jh), issue staging pair(s) for
//    tile t+1, raw barrier, setprio(1), 8-16 MFMA, setprio(0), raw barrier}.
// vmcnt(0) ONCE per tile at phase-0 entry: at that point only tile-t's own 8
// loads are outstanding (t+1's not yet issued), so the drain waits exactly for
// the needed data; pair-3's latency is covered by ~2 phases of compute.
// Hazards: stage writes buf[(t+1)&1]; its last readers (tile t-1 ds_reads)
// retired before t-1's phase barriers (lgkm-gated MFMA consumed them), and the
// stage sits after t's phase-0 VIS barrier => safe. Phase-0 ds_reads come
// AFTER the VIS barrier (all waves' loads landed) => safe.
// NOTE: never request >2 waves/SIMD — acc alone is 128 regs; at 4/SIMD
// (128-reg budget) the R2 experiment spilled: 2.4 GB/dispatch scratch, 3x slow.
template <int EPI, int KTOT, int KSPLIT, int NT>
__global__ __launch_bounds__(512, 2)
void k_gemm(const us* __restrict__ A0, const us* __restrict__ A1, int strideA,
            const us* __restrict__ Bw, const float* __restrict__ bias,
            us* __restrict__ outBf, float* __restrict__ outF,
            const float* __restrict__ sF, int writeF32) {
  __shared__ __align__(16) us sA[2][256 * 64];
  __shared__ __align__(16) us sB[2][256 * 64];
  int tid = threadIdx.x;
  int w = tid >> 6, l = tid & 63;
  int wr = w >> 2, wc = w & 3;
  int bid = blockIdx.x;
  int per = gridDim.x >> 3;
  int g = (bid & 7) * per + (bid >> 3);
  int mi, ni;
  if (NT == 1) { mi = g; ni = 0; }
  else         { mi = g / NT; ni = g - mi * NT; }
  int mBase = mi * 256, nBase = ni * 256;
  f32x4 acc[8][4] = {};
  bf16x8 af[2][4], bfr[2][2];

  auto stage_pair = [&](int t, int p) {
    int kt = t * 64, buf = t & 1;
    const us* aSrc; int kOff;
    if (kt < KSPLIT) { aSrc = A0; kOff = kt; }
    else             { aSrc = A1; kOff = kt - KSPLIT; }
    int row = p * 64 + (tid >> 3);
    int kb = ((tid & 7) * 16) ^ ((row & 7) << 4);   // pre-swizzled global source
    const char* ga = (const char*)(aSrc + (size_t)(mBase + row) * strideA + kOff) + kb;
    gload_lds16(ga, (char*)sA[buf] + row * 128 + (tid & 7) * 16);
    const char* gb = (const char*)(Bw + (size_t)(nBase + row) * KTOT + kt) + kb;
    gload_lds16(gb, (char*)sB[buf] + row * 128 + (tid & 7) * 16);
  };

  constexpr int NKT = KTOT / 64;

#define TILE_BODY(JMv)                                                         \
  {                                                                            \
    constexpr int M20 = (JMv) & 3, M21 = ((JMv) >> 2) & 3;                     \
    const us* Acur = sA[t & 1];                                                \
    const us* Bcur = sB[t & 1];                                                \
    bool more = (t + 1 < NKT);                                                 \
    /* ---- phase 0: (ih0, jh0) ---- */                                        \
    asm volatile("s_waitcnt vmcnt(0)" ::: "memory"); /* tile-t loads landed */ \
    raw_barrier();                                   /* VIS for buf t */       \
    quad_readA<0>(Acur, wr, l, af);                                            \
    quad_readB<0, M20>(Bcur, wc, l, bfr);                                      \
    if (more) { stage_pair(t + 1, 0); stage_pair(t + 1, 1); }                  \
    raw_barrier();                                                             \
    __builtin_amdgcn_s_setprio(1);                                             \
    quad_mma<0, 0, M20>(af, bfr, acc);                                         \
    __builtin_amdgcn_s_setprio(0);                                             \
    raw_barrier();                                                             \
    /* ---- phase 1: (ih0, jh1) ---- */                                        \
    quad_readB<1, M21>(Bcur, wc, l, bfr);                                      \
    if (more) stage_pair(t + 1, 2);                                            \
    raw_barrier();                                                             \
    __builtin_amdgcn_s_setprio(1);                                             \
    quad_mma<0, 1, M21>(af, bfr, acc);                                         \
    __builtin_amdgcn_s_setprio(0);                                             \
    raw_barrier();                                                             \
    /* ---- phase 2: (ih1, jh0) ---- */                                        \
    quad_readA<1>(Acur, wr, l, af);                                            \
    quad_readB<0, M20>(Bcur, wc, l, bfr);                                      \
    if (more) stage_pair(t + 1, 3);                                            \
    raw_barrier();                                                             \
    __builtin_amdgcn_s_setprio(1);                                             \
    quad_mma<1, 0, M20>(af, bfr, acc);                                         \
    __builtin_amdgcn_s_setprio(0);                                             \
    raw_barrier();                                                             \
    /* ---- phase 3: (ih1, jh1) ---- */                                        \
    quad_readB<1, M21>(Bcur, wc, l, bfr);                                      \
    raw_barrier();                                                             \
    __builtin_amdgcn_s_setprio(1);                                             \
    quad_mma<1, 1, M21>(af, bfr, acc);                                         \
    __builtin_amdgcn_s_setprio(0);                                             \
    /* no post-barrier: next tile's phase-0 vmcnt+VIS barrier subsumes it */   \
  }

  // prologue: all 4 staging pairs of tile 0
  stage_pair(0, 0); stage_pair(0, 1); stage_pair(0, 2); stage_pair(0, 3);
#pragma unroll
  for (int t = 0; t < NKT; ++t) {
    if (EPI == 2) {
      if (t * 64 < KSPLIT) TILE_BODY(0b0111)   // skip hn (j=3)
      else                 TILE_BODY(0b1011)   // skip xn (j=2)
    } else {
      TILE_BODY(0b1111)
    }
  }
#undef TILE_BODY

  int rBase0 = mBase + wr * 128;
  int cBase0 = nBase + wc * 64;
  if (EPI == 0 || EPI == 1) {
#pragma unroll
    for (int i = 0; i < 8; ++i)
#pragma unroll
      for (int j = 0; j < 4; ++j) {
        int col = cBase0 + j * 16 + (l & 15);
        int row0 = rBase0 + i * 16 + ((l >> 4) << 2);
        float bb = bias[col];
#pragma unroll
        for (int e = 0; e < 4; ++e) {
          float v = acc[i][j][e] + bb;
          size_t off = (size_t)(row0 + e) * 256 + col;
          outBf[off] = f2bf(v);
          if (EPI == 1) outF[off] = v;
        }
      }
  } else {
    // shuffle-free: j-fragment == gate (wave spans 64 gate-cols = 16 out cols)
    int outCol = ((nBase >> 6) + wc) * 16 + (l & 15);
    float b0 = bias[cBase0 + 0  + (l & 15)];
    float b1 = bias[cBase0 + 16 + (l & 15)];
    float b2 = bias[cBase0 + 32 + (l & 15)];
    float b3 = bias[cBase0 + 48 + (l & 15)];
#pragma unroll
    for (int i = 0; i < 8; ++i) {
      int row0 = rBase0 + i * 16 + ((l >> 4) << 2);
#pragma unroll
      for (int e = 0; e < 4; ++e) {
        float r = sigf(acc[i][0][e] + b0);
        float z = sigf(acc[i][1][e] + b1);
        float n = tanhfast(acc[i][2][e] + b2 + r * (acc[i][3][e] + b3));
        size_t off = (size_t)(row0 + e) * 256 + outCol;
        float sv = sF[off];
        float o = (1.f - z) * n + z * sv;
        if (writeF32) outF[off] = o;
        else          outBf[off] = f2bf(o);
      }
    }
  }
}

extern "C" void kernel_launch(void* const* d_in, const int* in_sizes, int n_in,
                              void* d_out, int out_size, void* d_ws, size_t ws_size,
                              hipStream_t stream) {
  const float* x    = (const float*)d_in[0];
  const int*   par  = (const int*)d_in[1];
  const int*   chd  = (const int*)d_in[2];
  const int*   cnt  = (const int*)d_in[3];
  const float* Wres = (const float*)d_in[4];
  const float* bres = (const float*)d_in[5];
  const float* Wpar = (const float*)d_in[6];
  const float* bpar = (const float*)d_in[7];
  const float* Wnbr = (const float*)d_in[8];
  const float* bnbr = (const float*)d_in[9];
  const float* Wih  = (const float*)d_in[10];
  const float* Whh  = (const float*)d_in[11];
  const float* bih  = (const float*)d_in[12];
  const float* bhh  = (const float*)d_in[13];

  char* ws = (char*)d_ws;
  size_t off = 0;
  auto alloc = [&](size_t sz) { char* p = ws + off; off += (sz + 255) & ~(size_t)255; return p; };
  us*    Wg   = (us*)alloc((size_t)1024 * 512 * 2);
  us*    Wcat = (us*)alloc((size_t)256 * 512 * 2);
  us*    Wr   = (us*)alloc((size_t)256 * 256 * 2);
  float* bcat = (float*)alloc(256 * 4);
  float* bg   = (float*)alloc(1024 * 4);
  us*    xbf  = (us*)alloc((size_t)MM * 256 * 2);  // reused as s_bf after resize
  us*    h0   = (us*)alloc((size_t)MM * 256 * 2);
  us*    h1   = (us*)alloc((size_t)MM * 256 * 2);
  us*    Acat = (us*)alloc((size_t)MM * 512 * 2);
  us*    sbf  = xbf;
  float* sF   = (float*)d_out;  // s_f32 scratch lives in d_out (overwritten at end)

  k_prep<<<256, 256, 0, stream>>>(Wres, Wpar, bpar, Wnbr, bnbr, Wih, Whh, bih, bhh,
                                  Wr, Wcat, bcat, Wg, bg);
  k_f2bf<<<(MM * 256 / 8) / 256, 256, 0, stream>>>(x, xbf, MM * 256 / 8);

  // h0 = x @ W_resize^T + b_resize   (M/256 = 256 blocks, single n-tile)
  k_gemm<0, 256, 256, 1><<<256, 512, 0, stream>>>(
      xbf, xbf, 256, Wr, bres, h0, nullptr, nullptr, 0);

  us* hc = h0;
  for (int it = 0; it < 3; ++it) {
    us* hn = (hc == h0) ? h1 : h0;
    k_gather<<<MM / 4, 256, 0, stream>>>(hc, par, chd, cnt, Acat);
    // s = [p|m] @ Wcat^T + bcat  -> s_bf + s_f32(in d_out)
    k_gemm<1, 512, 512, 1><<<256, 512, 0, stream>>>(
        Acat, Acat, 512, Wcat, bcat, sbf, sF, nullptr, 0);
    // fused GRU: [h|s] @ Wg^T, gate epilogue -> h_next (bf16) or d_out (f32, last)
    k_gemm<2, 512, 256, 4><<<1024, 512, 0, stream>>>(
        hc, sbf, 256, Wg, bg, hn, (float*)d_out, sF, (it == 2) ? 1 : 0);
    hc = hn;
  }
}

// Round 8
// 571.741 us; speedup vs baseline: 1.0143x; 1.0143x over previous
//
#include <hip/hip_runtime.h>

typedef unsigned short us;
typedef us us4 __attribute__((ext_vector_type(4)));
typedef us us8 __attribute__((ext_vector_type(8)));
typedef short bf16x8 __attribute__((ext_vector_type(8)));
typedef float f32x4 __attribute__((ext_vector_type(4)));

#define DEVI static __device__ __forceinline__

// constants for this problem instance
#define BB 16
#define NN 4096
#define PP 256
#define CC 8
#define MM (BB * NN)   // 65536

DEVI float bf2f(us u) { unsigned x = ((unsigned)u) << 16; return __builtin_bit_cast(float, x); }
DEVI us f2bf(float f) {
  unsigned x = __builtin_bit_cast(unsigned, f);
  x += 0x7fffu + ((x >> 16) & 1u);   // round to nearest even
  return (us)(x >> 16);
}

DEVI void gload_lds16(const void* g, void* l) {
  __builtin_amdgcn_global_load_lds(
      (const __attribute__((address_space(1))) void*)g,
      (__attribute__((address_space(3))) void*)l, 16, 0, 0);
}

DEVI float sigf(float x) { return 1.f / (1.f + __expf(-x)); }
DEVI float tanhfast(float a) {
  float aa = fabsf(a);
  float t = 1.f - 2.f / (1.f + __expf(2.f * aa));
  return copysignf(t, a);
}

// ---------------- weight prep: fp32 -> bf16, concatenated / gate-interleaved ----
// Wg layout (shuffle-free): row R -> J16 = R>>6, gate g = (R>>4)&3, c = R&15,
// output col j = J16*16 + c. Over K=512 ([h | s]):
//   g=0 (r):  [W_ih_r | W_hh_r]   g=1 (z): [W_ih_z | W_hh_z]
//   g=2 (xn): [W_ih_n | 0]        g=3 (hn): [0 | W_hh_n]
__global__ void k_prep(const float* __restrict__ Wres,
                       const float* __restrict__ Wpar, const float* __restrict__ bpar,
                       const float* __restrict__ Wnbr, const float* __restrict__ bnbr,
                       const float* __restrict__ Wih, const float* __restrict__ Whh,
                       const float* __restrict__ bih, const float* __restrict__ bhh,
                       us* __restrict__ Wr, us* __restrict__ Wcat, float* __restrict__ bcat,
                       us* __restrict__ Wg, float* __restrict__ bg) {
  int tid = blockIdx.x * blockDim.x + threadIdx.x;
  int nth = gridDim.x * blockDim.x;
  for (int i = tid; i < 256 * 256; i += nth) Wr[i] = f2bf(Wres[i]);
  for (int i = tid; i < 256 * 512; i += nth) {
    int o = i >> 9, k = i & 511;
    float v = (k < 256) ? Wpar[o * 256 + k] : Wnbr[o * 256 + (k - 256)];
    Wcat[i] = f2bf(v);
  }
  for (int i = tid; i < 256; i += nth) bcat[i] = bpar[i] + bnbr[i];
  for (int i = tid; i < 1024 * 512; i += nth) {
    int R = i >> 9, k = i & 511;
    int g = (R >> 4) & 3, j = ((R >> 6) << 4) + (R & 15);
    float v = 0.f;
    if (g == 0)      v = (k < 256) ? Wih[j * 256 + k]         : Whh[j * 256 + (k - 256)];
    else if (g == 1) v = (k < 256) ? Wih[(256 + j) * 256 + k] : Whh[(256 + j) * 256 + (k - 256)];
    else if (g == 2) v = (k < 256) ? Wih[(512 + j) * 256 + k] : 0.f;
    else             v = (k < 256) ? 0.f                      : Whh[(512 + j) * 256 + (k - 256)];
    Wg[i] = f2bf(v);
  }
  for (int i = tid; i < 1024; i += nth) {
    int g = (i >> 4) & 3, j = ((i >> 6) << 4) + (i & 15);
    float v;
    if (g == 0)      v = bih[j] + bhh[j];
    else if (g == 1) v = bih[256 + j] + bhh[256 + j];
    else if (g == 2) v = bih[512 + j];
    else             v = bhh[512 + j];
    bg[i] = v;
  }
}

// ---------------- x fp32 -> bf16 (vectorized) ----------------
__global__ __launch_bounds__(256) void k_f2bf(const float* __restrict__ x,
                                              us* __restrict__ o, int n8) {
  int i = blockIdx.x * blockDim.x + threadIdx.x;
  if (i >= n8) return;
  const float4* p = (const float4*)x + (size_t)i * 2;
  float4 a = p[0], b = p[1];
  us8 r;
  r[0] = f2bf(a.x); r[1] = f2bf(a.y); r[2] = f2bf(a.z); r[3] = f2bf(a.w);
  r[4] = f2bf(b.x); r[5] = f2bf(b.y); r[6] = f2bf(b.z); r[7] = f2bf(b.w);
  *(us8*)(o + (size_t)i * 8) = r;
}

// ---------------- gather: A_cat = [h[parent] | avg children h] (bf16) ----------
__global__ __launch_bounds__(256)
void k_gather(const us* __restrict__ h, const int* __restrict__ par,
              const int* __restrict__ chd, const int* __restrict__ cnt,
              us* __restrict__ Acat) {
  int wid = (blockIdx.x * blockDim.x + threadIdx.x) >> 6;  // one wave per node
  int l = threadIdx.x & 63;
  int m = wid;                       // 0..MM-1
  int b = m >> 12;                   // N = 4096
  int rowP = (b << 12) + par[m];
  us4 pv = *((const us4*)(h + ((size_t)rowP << 8)) + l);
  *((us4*)(Acat + ((size_t)m << 9)) + l) = pv;
  int c = cnt[m];
  float inv = 1.f / (float)c;
  const int* ch = chd + (size_t)m * CC;
  us4 cv[CC];
#pragma unroll
  for (int i = 0; i < CC; ++i) {
    int rowC = (b << 12) + ch[i];
    cv[i] = *((const us4*)(h + ((size_t)rowC << 8)) + l);
  }
  float a0 = 0.f, a1 = 0.f, a2 = 0.f, a3 = 0.f;
#pragma unroll
  for (int i = 0; i < CC; ++i) {
    float wgt = (i < c) ? 1.f : 0.f;
    a0 += wgt * bf2f(cv[i][0]); a1 += wgt * bf2f(cv[i][1]);
    a2 += wgt * bf2f(cv[i][2]); a3 += wgt * bf2f(cv[i][3]);
  }
  us4 nb;
  nb[0] = f2bf(a0 * inv); nb[1] = f2bf(a1 * inv);
  nb[2] = f2bf(a2 * inv); nb[3] = f2bf(a3 * inv);
  *((us4*)(Acat + ((size_t)m << 9) + 256) + l) = nb;
}

// ---------------- B fragments: global(L2-hot) -> VGPR, MFMA layout -------------
// B^T layout Bw[n][k]; lane l reads rows nBase+wc*64+j*16+(l&15), 8 bf16 at
// k = kt + ks*32 + (l>>4)*8. Coalesces as 16x64B segments — fine from L2.
template <int M4, int KTOTc>
DEVI void loadB(const us* __restrict__ Bw, int nBase, int wc, int l, int kt,
                bf16x8 (&b)[2][4]) {
#pragma unroll
  for (int ks = 0; ks < 2; ++ks)
#pragma unroll
    for (int j = 0; j < 4; ++j)
      if (M4 & (1 << j)) {
        int row = nBase + wc * 64 + j * 16 + (l & 15);
        b[ks][j] = *(const bf16x8*)(Bw + (size_t)row * KTOTc + kt + ks * 32 + ((l >> 4) * 8));
      }
}

// ---------------- MFMA K-tile: A from LDS (swizzled), B from regs --------------
template <int M4>
DEVI void mma_tile(const us* As, int l, const bf16x8 (&b)[2][4], f32x4 (&acc)[8][4]) {
#pragma unroll
  for (int ks = 0; ks < 2; ++ks) {
    bf16x8 af[8];
#pragma unroll
    for (int i = 0; i < 8; ++i) {
      int row = i * 16 + (l & 15);
      int kb = ((ks * 32 + (l >> 4) * 8) * 2) ^ ((row & 7) << 4);  // swizzled read
      af[i] = *(const bf16x8*)((const char*)As + row * 128 + kb);
    }
#pragma unroll
    for (int i = 0; i < 8; ++i)
#pragma unroll
      for (int j = 0; j < 4; ++j)
        if (M4 & (1 << j))
          acc[i][j] = __builtin_amdgcn_mfma_f32_16x16x32_bf16(af[i], b[ks][j], acc[i][j], 0, 0, 0);
  }
}

DEVI void raw_barrier() {
  __builtin_amdgcn_sched_barrier(0);
  __builtin_amdgcn_s_barrier();      // RAW barrier: no implicit vmcnt(0) drain
  __builtin_amdgcn_sched_barrier(0);
}

// ---------------- GEMM: C = A @ Bw^T (+bias), 128x256 tile, 4 waves ------------
// KEY STRUCTURE (R8): two 4-wave blocks co-resident per CU (LDS 32 KB/block,
// launch_bounds(256,2)) -> one block's MFMA fills the other's barrier/drain
// stalls (m114 cross-block overlap — lost in the 1-block 256² variants R5-R7).
// B operand skips LDS: global(L2-hot)->VGPR fragments, compiler-scheduled,
// immune to barrier discipline. LDS = A-only double buffer.
// Per K-tile: stageA(t+1) [4 gload_lds] -> loadB(t) [6-8 loads] ->
//   s_waitcnt vmcnt(4+NB) (A(t) landed; A(t+1)+B(t) IN FLIGHT) -> raw barrier
//   -> mma_tile (compiler lgkm/vmcnt-gates af/b reads) -> raw barrier.
// NOTE: acc alone is 128 VGPR -> never >2 waves/SIMD (R2: spill, 3x slow).
template <int EPI, int KTOT, int KSPLIT, int NT>
__global__ __launch_bounds__(256, 2)
void k_gemm(const us* __restrict__ A0, const us* __restrict__ A1, int strideA,
            const us* __restrict__ Bw, const float* __restrict__ bias,
            us* __restrict__ outBf, float* __restrict__ outF,
            const float* __restrict__ sF, int writeF32) {
  __shared__ __align__(16) us sA[2][128 * 64];
  int tid = threadIdx.x;
  int w = tid >> 6, l = tid & 63;
  int wc = w;                        // 4 waves across N; each owns 128x64
  int bid = blockIdx.x;
  int per = gridDim.x >> 3;
  int g = (bid & 7) * per + (bid >> 3);
  int mi, ni;
  if (NT == 1) { mi = g; ni = 0; }
  else         { mi = g / NT; ni = g - mi * NT; }
  int mBase = mi * 128, nBase = ni * 256;
  f32x4 acc[8][4] = {};
  bf16x8 bfr[2][4];

  auto stageA = [&](int t) {
    int kt = t * 64, buf = t & 1;
    const us* aSrc; int kOff;
    if (kt < KSPLIT) { aSrc = A0; kOff = kt; }
    else             { aSrc = A1; kOff = kt - KSPLIT; }
#pragma unroll
    for (int p = 0; p < 4; ++p) {
      int row = p * 32 + (tid >> 3);
      int kb = ((tid & 7) * 16) ^ ((row & 7) << 4);   // pre-swizzled global source
      const char* ga = (const char*)(aSrc + (size_t)(mBase + row) * strideA + kOff) + kb;
      gload_lds16(ga, (char*)sA[buf] + row * 128 + (tid & 7) * 16);
    }
  };

  constexpr int NKT = KTOT / 64;
  stageA(0);
#pragma unroll
  for (int t = 0; t < NKT; ++t) {
    bool more = (t + 1 < NKT);
    if (more) stageA(t + 1);
    if (EPI == 2) {
      if (t * 64 < KSPLIT) loadB<0b0111, KTOT>(Bw, nBase, wc, l, t * 64, bfr);
      else                 loadB<0b1011, KTOT>(Bw, nBase, wc, l, t * 64, bfr);
    } else {
      loadB<0b1111, KTOT>(Bw, nBase, wc, l, t * 64, bfr);
    }
    if (more) {
      if (EPI == 2) asm volatile("s_waitcnt vmcnt(10)" ::: "memory");
      else          asm volatile("s_waitcnt vmcnt(12)" ::: "memory");
    } else {
      if (EPI == 2) asm volatile("s_waitcnt vmcnt(6)" ::: "memory");
      else          asm volatile("s_waitcnt vmcnt(8)" ::: "memory");
    }
    raw_barrier();                     // all waves' A(t) LDS writes visible
    const us* Acur = sA[t & 1];
    if (EPI == 2) {
      if (t * 64 < KSPLIT) mma_tile<0b0111>(Acur, l, bfr, acc);  // skip hn (j=3)
      else                 mma_tile<0b1011>(Acur, l, bfr, acc);  // skip xn (j=2)
    } else {
      mma_tile<0b1111>(Acur, l, bfr, acc);
    }
    raw_barrier();                     // reads of buf done before restage
  }

  int rBase0 = mBase;                  // wr == 0 (wave spans all 128 M rows)
  int cBase0 = nBase + wc * 64;
  if (EPI == 0 || EPI == 1) {
#pragma unroll
    for (int i = 0; i < 8; ++i)
#pragma unroll
      for (int j = 0; j < 4; ++j) {
        int col = cBase0 + j * 16 + (l & 15);
        int row0 = rBase0 + i * 16 + ((l >> 4) << 2);
        float bb = bias[col];
#pragma unroll
        for (int e = 0; e < 4; ++e) {
          float v = acc[i][j][e] + bb;
          size_t off = (size_t)(row0 + e) * 256 + col;
          outBf[off] = f2bf(v);
          if (EPI == 1) outF[off] = v;
        }
      }
  } else {
    // shuffle-free: j-fragment == gate (wave spans 64 gate-cols = 16 out cols)
    int outCol = ((nBase >> 6) + wc) * 16 + (l & 15);
    float b0 = bias[cBase0 + 0  + (l & 15)];
    float b1 = bias[cBase0 + 16 + (l & 15)];
    float b2 = bias[cBase0 + 32 + (l & 15)];
    float b3 = bias[cBase0 + 48 + (l & 15)];
#pragma unroll
    for (int i = 0; i < 8; ++i) {
      int row0 = rBase0 + i * 16 + ((l >> 4) << 2);
#pragma unroll
      for (int e = 0; e < 4; ++e) {
        float r = sigf(acc[i][0][e] + b0);
        float z = sigf(acc[i][1][e] + b1);
        float n = tanhfast(acc[i][2][e] + b2 + r * (acc[i][3][e] + b3));
        size_t off = (size_t)(row0 + e) * 256 + outCol;
        float sv = sF[off];
        float o = (1.f - z) * n + z * sv;
        if (writeF32) outF[off] = o;
        else          outBf[off] = f2bf(o);
      }
    }
  }
}

extern "C" void kernel_launch(void* const* d_in, const int* in_sizes, int n_in,
                              void* d_out, int out_size, void* d_ws, size_t ws_size,
                              hipStream_t stream) {
  const float* x    = (const float*)d_in[0];
  const int*   par  = (const int*)d_in[1];
  const int*   chd  = (const int*)d_in[2];
  const int*   cnt  = (const int*)d_in[3];
  const float* Wres = (const float*)d_in[4];
  const float* bres = (const float*)d_in[5];
  const float* Wpar = (const float*)d_in[6];
  const float* bpar = (const float*)d_in[7];
  const float* Wnbr = (const float*)d_in[8];
  const float* bnbr = (const float*)d_in[9];
  const float* Wih  = (const float*)d_in[10];
  const float* Whh  = (const float*)d_in[11];
  const float* bih  = (const float*)d_in[12];
  const float* bhh  = (const float*)d_in[13];

  char* ws = (char*)d_ws;
  size_t off = 0;
  auto alloc = [&](size_t sz) { char* p = ws + off; off += (sz + 255) & ~(size_t)255; return p; };
  us*    Wg   = (us*)alloc((size_t)1024 * 512 * 2);
  us*    Wcat = (us*)alloc((size_t)256 * 512 * 2);
  us*    Wr   = (us*)alloc((size_t)256 * 256 * 2);
  float* bcat = (float*)alloc(256 * 4);
  float* bg   = (float*)alloc(1024 * 4);
  us*    xbf  = (us*)alloc((size_t)MM * 256 * 2);  // reused as s_bf after resize
  us*    h0   = (us*)alloc((size_t)MM * 256 * 2);
  us*    h1   = (us*)alloc((size_t)MM * 256 * 2);
  us*    Acat = (us*)alloc((size_t)MM * 512 * 2);
  us*    sbf  = xbf;
  float* sF   = (float*)d_out;  // s_f32 scratch lives in d_out (overwritten at end)

  k_prep<<<256, 256, 0, stream>>>(Wres, Wpar, bpar, Wnbr, bnbr, Wih, Whh, bih, bhh,
                                  Wr, Wcat, bcat, Wg, bg);
  k_f2bf<<<(MM * 256 / 8) / 256, 256, 0, stream>>>(x, xbf, MM * 256 / 8);

  // h0 = x @ W_resize^T + b_resize   (512 blocks = exactly 2/CU co-resident)
  k_gemm<0, 256, 256, 1><<<512, 256, 0, stream>>>(
      xbf, xbf, 256, Wr, bres, h0, nullptr, nullptr, 0);

  us* hc = h0;
  for (int it = 0; it < 3; ++it) {
    us* hn = (hc == h0) ? h1 : h0;
    k_gather<<<MM / 4, 256, 0, stream>>>(hc, par, chd, cnt, Acat);
    // s = [p|m] @ Wcat^T + bcat  -> s_bf + s_f32(in d_out)
    k_gemm<1, 512, 512, 1><<<512, 256, 0, stream>>>(
        Acat, Acat, 512, Wcat, bcat, sbf, sF, nullptr, 0);
    // fused GRU: [h|s] @ Wg^T, gate epilogue -> h_next (bf16) or d_out (f32, last)
    k_gemm<2, 512, 256, 4><<<2048, 256, 0, stream>>>(
        hc, sbf, 256, Wg, bg, hn, (float*)d_out, sF, (it == 2) ? 1 : 0);
    hc = hn;
  }
}